// Round 1
// baseline (421.678 us; speedup 1.0000x reference)
//
#include <hip/hip_runtime.h>

// LIF forward: x_seq [B=32, T=16, C=128, H=32, W=32] fp32 -> spikes, same shape.
// Recurrence per (b,c,h,w): u = 0.5*u + x_t; o_t = (u - 1 >= 0); u -= o_t.
// Memory-bound: 256 MB in + 256 MB out. One thread per 4 elements (float4).

constexpr int T_STEPS = 16;
constexpr int CHW     = 128 * 32 * 32;   // 131072 elements per [C,H,W] plane
constexpr int BATCH   = 32;
constexpr int PER_B4  = CHW / 4;         // 32768 float4 groups per plane

__global__ __launch_bounds__(256) void lif_fwd_kernel(
    const float* __restrict__ x, float* __restrict__ o)
{
    const int tid = blockIdx.x * blockDim.x + threadIdx.x;
    const int b   = tid / PER_B4;
    const int r   = tid - b * PER_B4;

    const float4* __restrict__ x4 = reinterpret_cast<const float4*>(x);
    float4* __restrict__       o4 = reinterpret_cast<float4*>(o);

    // element offset (in float4 units) of (b, t=0, chw-group r)
    size_t base = (size_t)b * (T_STEPS * PER_B4) + r;

    float ux = 0.f, uy = 0.f, uz = 0.f, uw = 0.f;

#pragma unroll
    for (int t = 0; t < T_STEPS; ++t) {
        float4 xv = x4[base + (size_t)t * PER_B4];

        ux = 0.5f * ux + xv.x;
        uy = 0.5f * uy + xv.y;
        uz = 0.5f * uz + xv.z;
        uw = 0.5f * uw + xv.w;

        float sx = (ux >= 1.0f) ? 1.0f : 0.0f;
        float sy = (uy >= 1.0f) ? 1.0f : 0.0f;
        float sz = (uz >= 1.0f) ? 1.0f : 0.0f;
        float sw = (uw >= 1.0f) ? 1.0f : 0.0f;

        float4 ov;
        ov.x = sx; ov.y = sy; ov.z = sz; ov.w = sw;
        o4[base + (size_t)t * PER_B4] = ov;

        ux -= sx; uy -= sy; uz -= sz; uw -= sw;
    }
}

extern "C" void kernel_launch(void* const* d_in, const int* in_sizes, int n_in,
                              void* d_out, int out_size, void* d_ws, size_t ws_size,
                              hipStream_t stream)
{
    const float* x = (const float*)d_in[0];
    float*       o = (float*)d_out;

    const int total_threads = BATCH * PER_B4;      // 1,048,576
    const int block = 256;
    const int grid  = total_threads / block;       // 4096

    lif_fwd_kernel<<<grid, block, 0, stream>>>(x, o);
}

// Round 3
// 414.099 us; speedup vs baseline: 1.0183x; 1.0183x over previous
//
#include <hip/hip_runtime.h>

// LIF forward: x_seq [B=32, T=16, C=128, H=32, W=32] fp32 -> spikes, same shape.
// Recurrence per (b,c,h,w): u = 0.5*u + x_t; o_t = (u - 1 >= 0); u -= o_t.
// Pure streaming kernel: 268 MB in + 268 MB out, zero reuse.
//   -> nontemporal loads/stores (nt) to bypass L2/LLC pollution (footprint >> 256 MiB L3).
//   -> T-loop split into 2x8 so only 8 float4 payloads are in flight per wave.
// NOTE: __builtin_nontemporal_* requires a NATIVE vector type (ext_vector_type),
// not HIP's struct float4.

typedef float floatx4 __attribute__((ext_vector_type(4)));

constexpr int T_STEPS = 16;
constexpr int CHW     = 128 * 32 * 32;   // 131072 elements per [C,H,W] plane
constexpr int BATCH   = 32;
constexpr int PER_B4  = CHW / 4;         // 32768 float4 groups per plane

__global__ __launch_bounds__(256) void lif_fwd_kernel(
    const float* __restrict__ x, float* __restrict__ o)
{
    const int tid = blockIdx.x * blockDim.x + threadIdx.x;
    const int b   = tid / PER_B4;
    const int r   = tid - b * PER_B4;

    const floatx4* __restrict__ x4 = reinterpret_cast<const floatx4*>(x);
    floatx4* __restrict__       o4 = reinterpret_cast<floatx4*>(o);

    // float4-offset of (b, t=0, group r)
    size_t base = (size_t)b * (T_STEPS * PER_B4) + (size_t)r;

    float ux = 0.f, uy = 0.f, uz = 0.f, uw = 0.f;

#pragma unroll 2
    for (int th = 0; th < 2; ++th) {
        // Stage 8 nontemporal loads (independent addresses -> all issued before
        // the dependent u-chain consumes them).
        floatx4 xv[8];
#pragma unroll
        for (int i = 0; i < 8; ++i) {
            xv[i] = __builtin_nontemporal_load(&x4[base + (size_t)(th * 8 + i) * PER_B4]);
        }
#pragma unroll
        for (int i = 0; i < 8; ++i) {
            ux = 0.5f * ux + xv[i].x;
            uy = 0.5f * uy + xv[i].y;
            uz = 0.5f * uz + xv[i].z;
            uw = 0.5f * uw + xv[i].w;

            float sx = (ux >= 1.0f) ? 1.0f : 0.0f;
            float sy = (uy >= 1.0f) ? 1.0f : 0.0f;
            float sz = (uz >= 1.0f) ? 1.0f : 0.0f;
            float sw = (uw >= 1.0f) ? 1.0f : 0.0f;

            floatx4 ov;
            ov.x = sx; ov.y = sy; ov.z = sz; ov.w = sw;
            __builtin_nontemporal_store(ov, &o4[base + (size_t)(th * 8 + i) * PER_B4]);

            ux -= sx; uy -= sy; uz -= sz; uw -= sw;
        }
    }
}

extern "C" void kernel_launch(void* const* d_in, const int* in_sizes, int n_in,
                              void* d_out, int out_size, void* d_ws, size_t ws_size,
                              hipStream_t stream)
{
    const float* x = (const float*)d_in[0];
    float*       o = (float*)d_out;

    const int total_threads = BATCH * PER_B4;      // 1,048,576
    const int block = 256;
    const int grid  = total_threads / block;       // 4096

    lif_fwd_kernel<<<grid, block, 0, stream>>>(x, o);
}

// Round 4
// 413.414 us; speedup vs baseline: 1.0200x; 1.0017x over previous
//
#include <hip/hip_runtime.h>

// LIF forward: x_seq [B=32, T=16, C=128, H=32, W=32] fp32 -> spikes, same shape.
// Recurrence per (b,c,h,w): u = 0.5*u + x_t; o_t = (u - 1 >= 0); u -= o_t.
// Pure streaming kernel: 268 MB in + 268 MB out, zero reuse (footprint >> 256 MiB L3).
//   -> nontemporal loads/stores (nt flag) to bypass cache pollution.
//   -> FULL 16-deep load staging: all 16 t-plane loads issued before the
//      dependent u-chain consumes them (16 KB in flight per wave; ~80 VGPRs
//      -> ~6 waves/SIMD, still far above Little's-law requirement).
// VALU budget: ~20 inst per 2 KB traffic per wave -> ~205 B/cyc/CU capability
// vs ~21 B/cyc/CU needed at 6.4 TB/s; compute cannot be the limiter.

typedef float floatx4 __attribute__((ext_vector_type(4)));

constexpr int T_STEPS = 16;
constexpr int CHW     = 128 * 32 * 32;   // 131072 elements per [C,H,W] plane
constexpr int BATCH   = 32;
constexpr int PER_B4  = CHW / 4;         // 32768 float4 groups per plane

__global__ __launch_bounds__(256) void lif_fwd_kernel(
    const float* __restrict__ x, float* __restrict__ o)
{
    const int tid = blockIdx.x * blockDim.x + threadIdx.x;
    const int b   = tid >> 15;            // tid / PER_B4
    const int r   = tid & (PER_B4 - 1);   // tid % PER_B4

    const floatx4* __restrict__ x4 = reinterpret_cast<const floatx4*>(x);
    floatx4* __restrict__       o4 = reinterpret_cast<floatx4*>(o);

    // float4-offset of (b, t=0, group r)
    const size_t base = (size_t)b * (T_STEPS * PER_B4) + (size_t)r;

    // Stage ALL 16 loads up front — independent addresses, maximum MLP.
    floatx4 xv[T_STEPS];
#pragma unroll
    for (int t = 0; t < T_STEPS; ++t) {
        xv[t] = __builtin_nontemporal_load(&x4[base + (size_t)t * PER_B4]);
    }

    float ux = 0.f, uy = 0.f, uz = 0.f, uw = 0.f;

#pragma unroll
    for (int t = 0; t < T_STEPS; ++t) {
        ux = 0.5f * ux + xv[t].x;
        uy = 0.5f * uy + xv[t].y;
        uz = 0.5f * uz + xv[t].z;
        uw = 0.5f * uw + xv[t].w;

        float sx = (ux >= 1.0f) ? 1.0f : 0.0f;
        float sy = (uy >= 1.0f) ? 1.0f : 0.0f;
        float sz = (uz >= 1.0f) ? 1.0f : 0.0f;
        float sw = (uw >= 1.0f) ? 1.0f : 0.0f;

        floatx4 ov;
        ov.x = sx; ov.y = sy; ov.z = sz; ov.w = sw;
        __builtin_nontemporal_store(ov, &o4[base + (size_t)t * PER_B4]);

        ux -= sx; uy -= sy; uz -= sz; uw -= sw;
    }
}

extern "C" void kernel_launch(void* const* d_in, const int* in_sizes, int n_in,
                              void* d_out, int out_size, void* d_ws, size_t ws_size,
                              hipStream_t stream)
{
    const float* x = (const float*)d_in[0];
    float*       o = (float*)d_out;

    const int total_threads = BATCH * PER_B4;      // 1,048,576
    const int block = 256;
    const int grid  = total_threads / block;       // 4096

    lif_fwd_kernel<<<grid, block, 0, stream>>>(x, o);
}